// Round 9
// baseline (197.693 us; speedup 1.0000x reference)
//
#include <hip/hip_runtime.h>
#include <hip/hip_bf16.h>

// AttentionRefinementModule: cumsum(excl,t) -> conv5x5(16->32) -> +b,relu ->
// mask0 -> 1x1 proj(32->8) -> masked BN -> permute.
// cumsum inputs first (conv commutes with cumsum); MFMA conv over 1024 images.
// R9: 8-row blocks (12x68x16 img = 26KB, block 32.3KB LDS) => 4 blocks/CU =
// 16 waves/CU (4/SIMD), up from 3/SIMD. Kernel is latency-bound (no pipe >50%,
// VGPR pinned at 84 across 5 structurally-different rounds => compiler won't
// deepen ILP); TLP is the remaining lever. R6 inner loop restored (setprio
// kept: R6 114 vs R8-no-setprio 120; independent blocks = T5's good regime).

typedef __attribute__((ext_vector_type(4))) float f32x4;
typedef __attribute__((ext_vector_type(8))) short short8;
typedef __attribute__((ext_vector_type(8))) unsigned short u16x8;

#define B_   8
#define NH   8
#define T_   128
#define H_   32
#define W_   64
#define L_   2048
#define CIN  16
#define DCC  32
#define WSTR 420   // K stride (elems) of weight rows (416 used + pad)

__device__ __forceinline__ unsigned short f2h(float f){
  _Float16 h = (_Float16)f;
  return __builtin_bit_cast(unsigned short, h);
}
__device__ __forceinline__ float h2f(unsigned short u){
  _Float16 h = __builtin_bit_cast(_Float16, u);
  return (float)h;
}
__device__ __forceinline__ unsigned pkrtz(float a, float b){
  return __builtin_bit_cast(unsigned, __builtin_amdgcn_cvt_pkrtz(a, b));
}
// 2-bit swizzle: bits[4:5] ^= bits[7:8]. Adding multiples of 512 commutes,
// so ds_read immediate offsets (mt steps of 512 B) remain valid.
__device__ __forceinline__ int swz(int a){ return a ^ ((a >> 3) & 0x30); }

// ---------------- K_front: cumsum (blocks 0..255) + prep (256..304) --------
__global__ void k_front(const float* __restrict__ prev,
                        const float* __restrict__ curr,
                        uint2* __restrict__ cum2,
                        const float* __restrict__ convw,
                        const float* __restrict__ projw,
                        const void* __restrict__ mraw,
                        unsigned short* __restrict__ Wt,
                        unsigned short* __restrict__ Pt,
                        unsigned char* __restrict__ mB,
                        float* __restrict__ cntOut)
{
  int tid = threadIdx.x;
  int blk = blockIdx.x;
  if (blk < 256){
    // exclusive cumsum over t, fp32 -> fp16, 4 px/thread
    int gid = blk * 256 + tid;                   // 0..65535
    int p4 = gid & 511;                          // quad: px = 4*p4
    int ci = (gid >> 9) & 15;
    int b  = gid >> 13;
    const float* src = ((ci < 8)
        ? prev + ((size_t)(b*8 + ci) * T_) * L_
        : curr + ((size_t)(b*8 + ci - 8) * T_) * L_) + p4*4;
    uint2* dst = cum2 + ((size_t)(b*CIN + ci) * T_) * (L_/4) + p4;
    float a0 = 0.f, a1 = 0.f, a2 = 0.f, a3 = 0.f;
    #pragma unroll 4
    for (int t = 0; t < T_; t++){
      uint2 o;
      o.x = (unsigned)f2h(a0) | ((unsigned)f2h(a1) << 16);
      o.y = (unsigned)f2h(a2) | ((unsigned)f2h(a3) << 16);
      dst[(size_t)t * (L_/4)] = o;               // exclusive
      f32x4 v = *(const f32x4*)(src + (size_t)t * L_);
      a0 += v.x; a1 += v.y; a2 += v.z; a3 += v.w;
    }
    return;
  }
  int blk2 = blk - 256;
  if (blk2 < 32){
    // Wt row co, dy-paired K layout:
    // k = g*32 + kb*8 + j ; h = kb>>1 ; ci = (kb&1)*8 + j
    // g<10: dx = g>>1, dy = (g&1)*2 + h
    // g>=10: dy = 4, dx = 2*(g-10) + h  (dx>4 => zero pad)
    int co = blk2;
    for (int k = tid; k < WSTR; k += 256){
      float v = 0.f;
      if (k < 416){
        int g  = k >> 5, kk = k & 31;
        int kb = kk >> 3, j = kk & 7;
        int ci = (kb & 1)*8 + j;
        int h  = kb >> 1;
        int dy, dx, valid = 1;
        if (g < 10){ dx = g >> 1; dy = (g & 1)*2 + h; }
        else { dy = 4; dx = 2*(g - 10) + h; if (dx > 4) valid = 0; }
        if (valid) v = convw[(((co*CIN + ci)*5 + dy)*5) + dx];
      }
      Wt[co*WSTR + k] = f2h(v);
    }
  } else if (blk2 == 32){
    // Pt[n][q] 16x32, rows 8..15 zero, col-permuted: q -> co = 16*(q&1)+(q>>1)
    for (int idx = tid; idx < 16*32; idx += 256){
      int n = idx >> 5, q = idx & 31;
      float v = (n < 8) ? projw[n*32 + 16*(q & 1) + (q >> 1)] : 0.f;
      Pt[idx] = f2h(v);
    }
  } else {
    __shared__ int s_flags;
    __shared__ int s_cnt;
    if (tid == 0){ s_flags = 0; s_cnt = 0; }
    __syncthreads();
    const unsigned* w = (const unsigned*)mraw;
    int fl = 0;
    for (int i = tid; i < 4096; i += 256){       // scan 16KB worth of words
      unsigned v = w[i];
      if (v == 0x3F800000u) fl |= 2;             // float 1.0 pattern
      else if (v > 1u)      fl |= 1;             // packed-byte pattern
      else if (v == 1u)     fl |= 4;             // i32 "true" pattern
    }
    if (fl) atomicOr(&s_flags, fl);
    __syncthreads();
    int flags = s_flags;
    int mode = (flags & 1) ? 0 : ((flags & 2) ? 2 : ((flags & 4) ? 1 : 0));
    int c = 0;
    int base = (blk2 - 33) * 1024;
    for (int k = 0; k < 4; k++){
      int i = base + k*256 + tid;
      int m;
      if (mode == 0)      m = (((const unsigned char*)mraw)[i] != 0);
      else if (mode == 2) m = (((const float*)mraw)[i] != 0.f);
      else                m = (((const int*)mraw)[i] != 0);
      mB[i] = (unsigned char)m;
      c += 1 - m;
    }
    atomicAdd(&s_cnt, c);
    __syncthreads();
    if (tid == 0) atomicAdd(cntOut, 128.0f * (float)s_cnt);
  }
}

// ---------------- K_conv: MFMA conv + bias/relu/mask + proj + stats --------
// One block = one 8-row slice of one (b,t) image. 4 waves x 128px each.
// Weights read from global (L1-resident, 26.9KB); img strip staged in LDS.
__global__ __launch_bounds__(256, 4) void k_conv(
    const unsigned short* __restrict__ cumIn,
    const unsigned short* __restrict__ Wt,
    const unsigned short* __restrict__ Pt,
    const unsigned char* __restrict__ mB,
    const float* __restrict__ convb,
    unsigned short* __restrict__ cov,
    float* __restrict__ slots)
{
  __shared__ alignas(16) unsigned short img[12*68*16];   // swizzled, 26112 B
  __shared__ alignas(16) unsigned short plds[16*32];     // 1024 B
  __shared__ alignas(16) unsigned sval[4][16*20];        // per-wave packed, 5120 B
  __shared__ unsigned long long mbl[8];                  // bit mask, 512 px

  const int tid  = threadIdx.x;
  const int bid  = blockIdx.x;
  const int oct  = bid & 3;                // 8-row slice index
  const int bt   = bid >> 2;
  const int t    = bt & 127;
  const int b    = bt >> 7;
  const int ylo  = oct * 8;
  const int lane = tid & 63;
  const int wv   = tid >> 6;
  const int mrow = lane & 15;
  const int kb   = lane >> 4;

  // mask bits for this slice: wave 0 ballots 8 x 64 px
  if (wv == 0){
    #pragma unroll
    for (int k2 = 0; k2 < 8; k2++){
      int m = mB[b*L_ + oct*512 + k2*64 + lane];
      unsigned long long bal = __ballot(m != 0);
      if (lane == 0) mbl[k2] = bal;
    }
  } else if (wv == 1){
    const uint4* srcp = (const uint4*)Pt;
    uint4* dstp = (uint4*)plds;
    for (int i = lane; i < 64; i += 64) dstp[i] = srcp[i];
  }

  // zero-fill x-halo columns (x in {-2,-1,64,65} is always OOB -> 0)
  for (int it = tid; it < 384; it += 256){
    int cp  = it & 7;
    int xxi = (it >> 3) & 3;
    int yy  = it >> 5;                       // 0..11
    int xx  = (xxi < 2) ? xxi : 64 + xxi;    // 0,1,66,67
    int ad  = ((yy*68 + xx)*16 + 2*cp)*2;
    *(unsigned*)((char*)img + swz(ad)) = 0u;
  }
  // stage interior: thread = (yy, ci-pair, x-chunk of 8); 16B coalesced loads,
  // b32 LDS writes (2 ci packed via v_perm), 2-bit swizzle
  #pragma unroll
  for (int iter = 0; iter < 3; iter++){
    int it = iter*256 + tid;                 // 0..767
    int xc = it & 7;
    int cp = (it >> 3) & 7;
    int yy = it >> 6;                        // 0..11
    int y  = ylo - 2 + yy;
    uint4 r0 = (uint4){0,0,0,0}, r1 = (uint4){0,0,0,0};
    if (y >= 0 && y < H_){
      const unsigned short* rp = cumIn + (((size_t)(b*CIN + 2*cp) * T_ + t) * L_) + y*W_ + xc*8;
      r0 = *(const uint4*)rp;
      r1 = *(const uint4*)(rp + (size_t)T_ * L_);   // next ci plane
    }
    int sbase = ((yy*68 + 2 + xc*8)*16 + 2*cp)*2;
    unsigned rr0[4] = {r0.x, r0.y, r0.z, r0.w};
    unsigned rr1[4] = {r1.x, r1.y, r1.z, r1.w};
    #pragma unroll
    for (int d = 0; d < 4; d++){
      unsigned wl = __builtin_amdgcn_perm(rr1[d], rr0[d], 0x05040100u); // j=2d
      unsigned wh = __builtin_amdgcn_perm(rr1[d], rr0[d], 0x07060302u); // j=2d+1
      *(unsigned*)((char*)img + swz(sbase + (2*d  )*32)) = wl;
      *(unsigned*)((char*)img + swz(sbase + (2*d+1)*32)) = wh;
    }
  }
  __syncthreads();

  const float cb0 = convb[mrow];
  const float cb1 = convb[mrow + 16];
  const short8 pbf = *(const short8*)&plds[mrow*32 + kb*8];  // proj B-frag
  const unsigned short* Wg = Wt + mrow*WSTR + kb*8;          // weight row base
  const char* imgc = (const char*)img;

  // per-lane tap byte-offsets for all 13 k-groups (dy-paired layout)
  int offs_[13];
  {
    const int h = kb >> 1;
    #pragma unroll
    for (int g = 0; g < 13; g++){
      int dy, dx;
      if (g < 10){ dx = g >> 1; dy = (g & 1)*2 + h; }
      else { dy = 4; dx = 2*(g - 10) + h; if (dx > 4) dx = 4; } // pad: W=0
      offs_[g] = (dy*68 + dx)*32 + (kb & 1)*16;
    }
  }

  float ssum = 0.f, ssq = 0.f;

  {
    // opaque zero: keeps B-loads un-hoisted/un-clustered (VGPR fit at cap 128)
    int wofs = 0;
    asm volatile("" : "+v"(wofs));
    const int pbase = wv*128;
    const unsigned long long mw0 = mbl[(pbase >> 6)];
    const unsigned long long mw1 = mbl[(pbase >> 6) + 1];
    const int base_u = ((pbase >> 6)*68 + mrow)*32;   // unswizzled byte base
    f32x4 acc[8][2];
    #pragma unroll
    for (int mt = 0; mt < 8; mt++){ acc[mt][0] = (f32x4)0.f; acc[mt][1] = (f32x4)0.f; }

    #pragma unroll
    for (int ks = 0; ks < 13; ks++){
      short8 bfa = *(const short8*)(Wg + wofs + ks*32);          // co 0..15
      short8 bfb = *(const short8*)(Wg + wofs + 6720 + ks*32);   // co 16..31
      const char* p0 = imgc + swz(base_u + offs_[ks]);
      const char* p1 = imgc + swz(base_u + 2176 + offs_[ks]);
      short8 a[8];
      a[0] = *(const short8*)(p0);
      a[1] = *(const short8*)(p0 + 512);
      a[2] = *(const short8*)(p0 + 1024);
      a[3] = *(const short8*)(p0 + 1536);
      a[4] = *(const short8*)(p1);
      a[5] = *(const short8*)(p1 + 512);
      a[6] = *(const short8*)(p1 + 1024);
      a[7] = *(const short8*)(p1 + 1536);
      __builtin_amdgcn_s_setprio(1);
      #pragma unroll
      for (int mt = 0; mt < 8; mt++){
        acc[mt][0] = __builtin_amdgcn_mfma_f32_16x16x32_f16(a[mt], bfa, acc[mt][0], 0, 0, 0);
        acc[mt][1] = __builtin_amdgcn_mfma_f32_16x16x32_f16(a[mt], bfb, acc[mt][1], 0, 0, 0);
      }
      __builtin_amdgcn_s_setprio(0);
    }

    // epilogue: bias+relu+mask -> packed fp16 pairs in sval (transpose) ->
    // proj MFMA (K=32, P columns pre-permuted) -> cov store + stats.
    // Single buffer: proj(mt-1) reads are issued BEFORE store(mt) writes;
    // same-wave LDS ops complete in order, compiler preserves aliased order.
    unsigned* sv = &sval[wv][0];
    #pragma unroll
    for (int mt = 0; mt <= 8; mt++){
      if (mt >= 1){
        const int m = mt - 1;
        short8 pa = *(const short8*)&sv[mrow*20 + kb*4];
        f32x4 pc = (f32x4)0.f;
        pc = __builtin_amdgcn_mfma_f32_16x16x32_f16(pa, pbf, pc, 0, 0, 0);
        if (mrow < 8){
          const unsigned long long mwm = (m < 4) ? mw0 : mw1;
          size_t covbase = (((size_t)bt*NH + mrow) * L_) + oct*512 + pbase + m*16 + kb*4;
          uint2 st;
          st.x = pkrtz(pc[0], pc[1]);
          st.y = pkrtz(pc[2], pc[3]);
          *(uint2*)&cov[covbase] = st;
          #pragma unroll
          for (int r = 0; r < 4; r++){
            int bi = (m*16 + kb*4 + r) & 63;
            if (!((mwm >> bi) & 1)){ ssum += pc[r]; ssq += pc[r]*pc[r]; }
          }
        }
      }
      if (mt < 8){
        const unsigned long long mw = (mt < 4) ? mw0 : mw1;
        #pragma unroll
        for (int r = 0; r < 4; r += 2){
          int bi0 = (mt*16 + kb*4 + r)     & 63;
          int bi1 = (mt*16 + kb*4 + r + 1) & 63;
          float v0a = fmaxf(acc[mt][0][r]   + cb0, 0.f);
          float v1a = fmaxf(acc[mt][1][r]   + cb1, 0.f);
          float v0b = fmaxf(acc[mt][0][r+1] + cb0, 0.f);
          float v1b = fmaxf(acc[mt][1][r+1] + cb1, 0.f);
          if ((mw >> bi0) & 1){ v0a = 0.f; v1a = 0.f; }
          if ((mw >> bi1) & 1){ v0b = 0.f; v1b = 0.f; }
          sv[(kb*4 + r    )*20 + mrow] = pkrtz(v0a, v1a);
          sv[(kb*4 + r + 1)*20 + mrow] = pkrtz(v0b, v1b);
        }
      }
    }
  }

  // stats: fold kb groups (lanes mrow, mrow+16, mrow+32, mrow+48)
  ssum += __shfl_xor(ssum, 16);
  ssum += __shfl_xor(ssum, 32);
  ssq  += __shfl_xor(ssq, 16);
  ssq  += __shfl_xor(ssq, 32);
  if (lane < 8){
    atomicAdd(&slots[(bid & 7)*16 + lane],     ssum);
    atomicAdd(&slots[(bid & 7)*16 + 8 + lane], ssq);
  }
}

// ---------------- K_stats: finalize BN -> per-channel affine ---------------
__global__ void k_stats(const float* __restrict__ slots,
                        const float* __restrict__ cntp,
                        const float* __restrict__ gamma,
                        const float* __restrict__ beta,
                        float* __restrict__ ab)
{
  int tid = threadIdx.x;
  if (tid < 8){
    double s = 0.0, q = 0.0;
    for (int i = 0; i < 8; i++){
      s += (double)slots[i*16 + tid];
      q += (double)slots[i*16 + 8 + tid];
    }
    double cnt  = (double)fmaxf(*cntp, 1.0f);
    double mean = s / cnt;
    double var  = q / cnt - mean*mean;
    float inv = (float)(1.0 / sqrt(var + 1e-5));
    float A = gamma[tid] * inv;
    float Bc = beta[tid] - (float)mean * A;
    ab[tid]     = A;
    ab[8 + tid] = Bc;
  }
}

// ---------------- K_out: normalize + (b,t,n)->(b,n,t) permute --------------
__global__ void k_out(const unsigned short* __restrict__ cov,
                      const unsigned char* __restrict__ mB,
                      const float* __restrict__ ab,
                      float* __restrict__ out)
{
  size_t gid = (size_t)blockIdx.x * 256 + threadIdx.x;
  size_t e = gid * 8;                               // out element base
  int px = (int)(e & 2047);
  size_t r = e >> 11;
  int t = (int)(r & 127); r >>= 7;
  int n = (int)(r & 7);
  int b = (int)(r >> 3);
  const unsigned short* cp = cov + ((((size_t)b*T_ + t)*NH + n) << 11) + px;
  u16x8 cv = *(const u16x8*)cp;
  unsigned long long mm = *(const unsigned long long*)(mB + (size_t)b*L_ + px);
  float A = ab[n], Bc = ab[8 + n];
  float res[8];
  #pragma unroll
  for (int j = 0; j < 8; j++){
    float v = h2f(cv[j]);
    res[j] = ((mm >> (8*j)) & 0xFFull) ? v : (A*v + Bc);  // masked: raw (==0)
  }
  f32x4* o = (f32x4*)(out + e);
  o[0] = (f32x4){res[0], res[1], res[2], res[3]};
  o[1] = (f32x4){res[4], res[5], res[6], res[7]};
}

// ---------------------------------------------------------------------------
extern "C" void kernel_launch(void* const* d_in, const int* in_sizes, int n_in,
                              void* d_out, int out_size, void* d_ws, size_t ws_size,
                              hipStream_t stream)
{
  const float* prev  = (const float*)d_in[0];
  const float* curr  = (const float*)d_in[1];
  const void*  mraw  = d_in[2];
  // d_in[3] = h (unused, constant 32)
  const float* convw = (const float*)d_in[4];
  const float* convb = (const float*)d_in[5];
  const float* projw = (const float*)d_in[6];
  const float* gamma = (const float*)d_in[7];
  const float* beta  = (const float*)d_in[8];
  float* out = (float*)d_out;

  char* ws = (char*)d_ws;
  // layout (bytes): cumIn 67108864 | cov 33554432 | mB 16384 | Wt 26880 |
  //                 Pt 1024 | slots 512 | cnt 64 | ab 64
  unsigned short* cumIn = (unsigned short*)(ws);
  unsigned short* cov   = (unsigned short*)(ws + 67108864);
  unsigned char*  mB    = (unsigned char*) (ws + 100663296);
  unsigned short* Wt    = (unsigned short*)(ws + 100679680);
  unsigned short* Pt    = (unsigned short*)(ws + 100706560);
  float* slots          = (float*)(ws + 100707584);
  float* cntp           = (float*)(ws + 100708096);
  float* ab             = (float*)(ws + 100708160);
  if (ws_size < (size_t)100708224) return;   // clean failure if ws too small

  hipMemsetAsync(slots, 0, 640, stream);     // slots + cntp
  k_front <<<305,  256, 0, stream>>>(prev, curr, (uint2*)cumIn,
                                     convw, projw, mraw, Wt, Pt, mB, cntp);
  k_conv  <<<4096, 256, 0, stream>>>(cumIn, Wt, Pt, mB, convb, cov, slots);
  k_stats <<<1,    64,  0, stream>>>(slots, cntp, gamma, beta, ab);
  k_out   <<<8192, 256, 0, stream>>>(cov, mB, ab, out);
}

// Round 10
// 189.603 us; speedup vs baseline: 1.0427x; 1.0427x over previous
//
#include <hip/hip_runtime.h>
#include <hip/hip_bf16.h>

// AttentionRefinementModule: cumsum(excl,t) -> conv5x5(16->32) -> +b,relu ->
// mask0 -> 1x1 proj(32->8) -> masked BN -> permute.
// cumsum inputs first (conv commutes with cumsum); MFMA conv over 1024 images.
// R10: occupancy arc closed (2/3/4 waves/SIMD all ~114us => per-wave latency
// chain bound). Spend registers instead: launch_bounds(256,2) (cap 256),
// remove anti-LICM hack so all 26 B-frags hoist to regs (loaded once/wave),
// depth-1 A-prefetch hides LDS latency under MFMA. Grid/LDS = R6 (16-row).

typedef __attribute__((ext_vector_type(4))) float f32x4;
typedef __attribute__((ext_vector_type(8))) short short8;
typedef __attribute__((ext_vector_type(8))) unsigned short u16x8;

#define B_   8
#define NH   8
#define T_   128
#define H_   32
#define W_   64
#define L_   2048
#define CIN  16
#define DCC  32
#define WSTR 420   // K stride (elems) of weight rows (416 used + pad)

__device__ __forceinline__ unsigned short f2h(float f){
  _Float16 h = (_Float16)f;
  return __builtin_bit_cast(unsigned short, h);
}
__device__ __forceinline__ float h2f(unsigned short u){
  _Float16 h = __builtin_bit_cast(_Float16, u);
  return (float)h;
}
__device__ __forceinline__ unsigned pkrtz(float a, float b){
  return __builtin_bit_cast(unsigned, __builtin_amdgcn_cvt_pkrtz(a, b));
}
// 2-bit swizzle: bits[4:5] ^= bits[7:8]. Adding multiples of 512 commutes,
// so ds_read immediate offsets (mt steps of 512 B) remain valid.
__device__ __forceinline__ int swz(int a){ return a ^ ((a >> 3) & 0x30); }

// ---------------- K_front: cumsum (blocks 0..255) + prep (256..304) --------
__global__ void k_front(const float* __restrict__ prev,
                        const float* __restrict__ curr,
                        uint2* __restrict__ cum2,
                        const float* __restrict__ convw,
                        const float* __restrict__ projw,
                        const void* __restrict__ mraw,
                        unsigned short* __restrict__ Wt,
                        unsigned short* __restrict__ Pt,
                        unsigned char* __restrict__ mB,
                        float* __restrict__ cntOut)
{
  int tid = threadIdx.x;
  int blk = blockIdx.x;
  if (blk < 256){
    // exclusive cumsum over t, fp32 -> fp16, 4 px/thread
    int gid = blk * 256 + tid;                   // 0..65535
    int p4 = gid & 511;                          // quad: px = 4*p4
    int ci = (gid >> 9) & 15;
    int b  = gid >> 13;
    const float* src = ((ci < 8)
        ? prev + ((size_t)(b*8 + ci) * T_) * L_
        : curr + ((size_t)(b*8 + ci - 8) * T_) * L_) + p4*4;
    uint2* dst = cum2 + ((size_t)(b*CIN + ci) * T_) * (L_/4) + p4;
    float a0 = 0.f, a1 = 0.f, a2 = 0.f, a3 = 0.f;
    #pragma unroll 4
    for (int t = 0; t < T_; t++){
      uint2 o;
      o.x = (unsigned)f2h(a0) | ((unsigned)f2h(a1) << 16);
      o.y = (unsigned)f2h(a2) | ((unsigned)f2h(a3) << 16);
      dst[(size_t)t * (L_/4)] = o;               // exclusive
      f32x4 v = *(const f32x4*)(src + (size_t)t * L_);
      a0 += v.x; a1 += v.y; a2 += v.z; a3 += v.w;
    }
    return;
  }
  int blk2 = blk - 256;
  if (blk2 < 32){
    // Wt row co, dy-paired K layout:
    // k = g*32 + kb*8 + j ; h = kb>>1 ; ci = (kb&1)*8 + j
    // g<10: dx = g>>1, dy = (g&1)*2 + h
    // g>=10: dy = 4, dx = 2*(g-10) + h  (dx>4 => zero pad)
    int co = blk2;
    for (int k = tid; k < WSTR; k += 256){
      float v = 0.f;
      if (k < 416){
        int g  = k >> 5, kk = k & 31;
        int kb = kk >> 3, j = kk & 7;
        int ci = (kb & 1)*8 + j;
        int h  = kb >> 1;
        int dy, dx, valid = 1;
        if (g < 10){ dx = g >> 1; dy = (g & 1)*2 + h; }
        else { dy = 4; dx = 2*(g - 10) + h; if (dx > 4) valid = 0; }
        if (valid) v = convw[(((co*CIN + ci)*5 + dy)*5) + dx];
      }
      Wt[co*WSTR + k] = f2h(v);
    }
  } else if (blk2 == 32){
    // Pt[n][q] 16x32, rows 8..15 zero, col-permuted: q -> co = 16*(q&1)+(q>>1)
    for (int idx = tid; idx < 16*32; idx += 256){
      int n = idx >> 5, q = idx & 31;
      float v = (n < 8) ? projw[n*32 + 16*(q & 1) + (q >> 1)] : 0.f;
      Pt[idx] = f2h(v);
    }
  } else {
    __shared__ int s_flags;
    __shared__ int s_cnt;
    if (tid == 0){ s_flags = 0; s_cnt = 0; }
    __syncthreads();
    const unsigned* w = (const unsigned*)mraw;
    int fl = 0;
    for (int i = tid; i < 4096; i += 256){       // scan 16KB worth of words
      unsigned v = w[i];
      if (v == 0x3F800000u) fl |= 2;             // float 1.0 pattern
      else if (v > 1u)      fl |= 1;             // packed-byte pattern
      else if (v == 1u)     fl |= 4;             // i32 "true" pattern
    }
    if (fl) atomicOr(&s_flags, fl);
    __syncthreads();
    int flags = s_flags;
    int mode = (flags & 1) ? 0 : ((flags & 2) ? 2 : ((flags & 4) ? 1 : 0));
    int c = 0;
    int base = (blk2 - 33) * 1024;
    for (int k = 0; k < 4; k++){
      int i = base + k*256 + tid;
      int m;
      if (mode == 0)      m = (((const unsigned char*)mraw)[i] != 0);
      else if (mode == 2) m = (((const float*)mraw)[i] != 0.f);
      else                m = (((const int*)mraw)[i] != 0);
      mB[i] = (unsigned char)m;
      c += 1 - m;
    }
    atomicAdd(&s_cnt, c);
    __syncthreads();
    if (tid == 0) atomicAdd(cntOut, 128.0f * (float)s_cnt);
  }
}

// compile-time tap-group byte offsets (dy-paired layout), h/lo added runtime
__device__ __constant__ const int kCg[13] =
  {0, 4352, 32, 4384, 64, 4416, 96, 4448, 128, 4480, 8704, 8768, 8832};

// ---------------- K_conv: MFMA conv + bias/relu/mask + proj + stats --------
// One block = half of one (b,t) image (16 rows). 4 waves x 256px each.
// B-weights live in registers (26 x short8, hoisted); img staged in LDS.
__global__ __launch_bounds__(256, 2) void k_conv(
    const unsigned short* __restrict__ cumIn,
    const unsigned short* __restrict__ Wt,
    const unsigned short* __restrict__ Pt,
    const unsigned char* __restrict__ mB,
    const float* __restrict__ convb,
    unsigned short* __restrict__ cov,
    float* __restrict__ slots)
{
  __shared__ alignas(16) unsigned short img[20*68*16];   // swizzled, 43520 B
  __shared__ alignas(16) unsigned short plds[16*32];     // 1024 B
  __shared__ alignas(16) unsigned sval[4][16*20];        // per-wave packed, 5120 B
  __shared__ unsigned long long mbl[16];                 // bit mask, 1024 px

  const int tid  = threadIdx.x;
  const int bid  = blockIdx.x;
  const int half = bid & 1;
  const int bt   = bid >> 1;
  const int t    = bt & 127;
  const int b    = bt >> 7;
  const int ylo  = half * 16;
  const int lane = tid & 63;
  const int wv   = tid >> 6;
  const int mrow = lane & 15;
  const int kb   = lane >> 4;

  // mask bits for this half-image: wave 0 ballots 16 x 64 px
  if (wv == 0){
    #pragma unroll
    for (int k2 = 0; k2 < 16; k2++){
      int m = mB[b*L_ + half*1024 + k2*64 + lane];
      unsigned long long bal = __ballot(m != 0);
      if (lane == 0) mbl[k2] = bal;
    }
  } else if (wv == 1){
    const uint4* srcp = (const uint4*)Pt;
    uint4* dstp = (uint4*)plds;
    for (int i = lane; i < 64; i += 64) dstp[i] = srcp[i];
  }

  // zero-fill x-halo columns (x in {-2,-1,64,65} is always OOB -> 0)
  for (int it = tid; it < 640; it += 256){
    int cp  = it & 7;
    int xxi = (it >> 3) & 3;
    int yy  = it >> 5;                       // 0..19
    int xx  = (xxi < 2) ? xxi : 64 + xxi;    // 0,1,66,67
    int ad  = ((yy*68 + xx)*16 + 2*cp)*2;
    *(unsigned*)((char*)img + swz(ad)) = 0u;
  }
  // stage interior: thread = (yy, ci-pair, x-chunk of 8); 16B coalesced loads,
  // b32 LDS writes (2 ci packed via v_perm), 2-bit swizzle
  #pragma unroll
  for (int iter = 0; iter < 5; iter++){
    int it = iter*256 + tid;                 // 0..1279
    int xc = it & 7;
    int cp = (it >> 3) & 7;
    int yy = it >> 6;                        // 0..19
    int y  = ylo - 2 + yy;
    uint4 r0 = (uint4){0,0,0,0}, r1 = (uint4){0,0,0,0};
    if (y >= 0 && y < H_){
      const unsigned short* rp = cumIn + (((size_t)(b*CIN + 2*cp) * T_ + t) * L_) + y*W_ + xc*8;
      r0 = *(const uint4*)rp;
      r1 = *(const uint4*)(rp + (size_t)T_ * L_);   // next ci plane
    }
    int sbase = ((yy*68 + 2 + xc*8)*16 + 2*cp)*2;
    unsigned rr0[4] = {r0.x, r0.y, r0.z, r0.w};
    unsigned rr1[4] = {r1.x, r1.y, r1.z, r1.w};
    #pragma unroll
    for (int d = 0; d < 4; d++){
      unsigned wl = __builtin_amdgcn_perm(rr1[d], rr0[d], 0x05040100u); // j=2d
      unsigned wh = __builtin_amdgcn_perm(rr1[d], rr0[d], 0x07060302u); // j=2d+1
      *(unsigned*)((char*)img + swz(sbase + (2*d  )*32)) = wl;
      *(unsigned*)((char*)img + swz(sbase + (2*d+1)*32)) = wh;
    }
  }

  const float cb0 = convb[mrow];
  const float cb1 = convb[mrow + 16];
  const short8 pbf = *(const short8*)&plds[mrow*32 + kb*8];  // proj B-frag
  const unsigned short* Wg = Wt + mrow*WSTR + kb*8;          // weight row base
  const char* imgc = (const char*)img;

  // hoist ALL B-fragments into registers: loaded once per wave (no per-ks
  // global loads, no vmcnt waits in the main loop)
  short8 wA[13], wB[13];
  #pragma unroll
  for (int ks = 0; ks < 13; ks++){
    wA[ks] = *(const short8*)(Wg + ks*32);          // co 0..15
    wB[ks] = *(const short8*)(Wg + 6720 + ks*32);   // co 16..31
  }
  __syncthreads();

  // runtime offset bases (compile-time per-g constants in kCg):
  const int h  = kb >> 1;
  const int lo = (kb & 1)*16;
  const int rA = h*2176 + lo;   // g < 10  (h selects dy within pair)
  const int rB = h*32   + lo;   // g = 10,11 (h selects dx within pair)
  const int rC = lo;            // g = 12 (h part clamped, W=0)

  float ssum = 0.f, ssq = 0.f;

  #pragma unroll 1
  for (int c = 0; c < 2; c++){
    const int pbase = wv*256 + c*128;
    const unsigned long long mw0 = mbl[(pbase >> 6)];
    const unsigned long long mw1 = mbl[(pbase >> 6) + 1];
    const int base_u = ((pbase >> 6)*68 + mrow)*32;   // unswizzled byte base
    const int bA = base_u + rA, bB = base_u + rB, bC = base_u + rC;
    f32x4 acc[8][2];
    #pragma unroll
    for (int mt = 0; mt < 8; mt++){ acc[mt][0] = (f32x4)0.f; acc[mt][1] = (f32x4)0.f; }

    // depth-1 A-prefetch: issue next ks's 8 ds_reads before current MFMAs
    short8 av[8], nv[8];
    {
      const char* p0 = imgc + swz(bA + kCg[0]);
      const char* p1 = imgc + swz(bA + kCg[0] + 2176);
      av[0] = *(const short8*)(p0);
      av[1] = *(const short8*)(p0 + 512);
      av[2] = *(const short8*)(p0 + 1024);
      av[3] = *(const short8*)(p0 + 1536);
      av[4] = *(const short8*)(p1);
      av[5] = *(const short8*)(p1 + 512);
      av[6] = *(const short8*)(p1 + 1024);
      av[7] = *(const short8*)(p1 + 1536);
    }
    #pragma unroll
    for (int ks = 0; ks < 13; ks++){
      if (ks < 12){
        const int g1 = ks + 1;
        const int u  = (g1 < 10 ? bA : (g1 < 12 ? bB : bC)) + kCg[g1];
        const char* q0 = imgc + swz(u);
        const char* q1 = imgc + swz(u + 2176);
        nv[0] = *(const short8*)(q0);
        nv[1] = *(const short8*)(q0 + 512);
        nv[2] = *(const short8*)(q0 + 1024);
        nv[3] = *(const short8*)(q0 + 1536);
        nv[4] = *(const short8*)(q1);
        nv[5] = *(const short8*)(q1 + 512);
        nv[6] = *(const short8*)(q1 + 1024);
        nv[7] = *(const short8*)(q1 + 1536);
      }
      __builtin_amdgcn_s_setprio(1);
      #pragma unroll
      for (int mt = 0; mt < 8; mt++){
        acc[mt][0] = __builtin_amdgcn_mfma_f32_16x16x32_f16(av[mt], wA[ks], acc[mt][0], 0, 0, 0);
        acc[mt][1] = __builtin_amdgcn_mfma_f32_16x16x32_f16(av[mt], wB[ks], acc[mt][1], 0, 0, 0);
      }
      __builtin_amdgcn_s_setprio(0);
      #pragma unroll
      for (int i = 0; i < 8; i++) av[i] = nv[i];
    }

    // epilogue: bias+relu+mask -> packed fp16 pairs in sval (transpose) ->
    // proj MFMA (K=32, P columns pre-permuted) -> cov store + stats.
    // Single buffer: proj(mt-1) reads are issued BEFORE store(mt) writes;
    // same-wave LDS ops complete in order, compiler preserves aliased order.
    unsigned* sv = &sval[wv][0];
    #pragma unroll
    for (int mt = 0; mt <= 8; mt++){
      if (mt >= 1){
        const int m = mt - 1;
        short8 pa = *(const short8*)&sv[mrow*20 + kb*4];
        f32x4 pc = (f32x4)0.f;
        pc = __builtin_amdgcn_mfma_f32_16x16x32_f16(pa, pbf, pc, 0, 0, 0);
        if (mrow < 8){
          const unsigned long long mwm = (m < 4) ? mw0 : mw1;
          size_t covbase = (((size_t)bt*NH + mrow) * L_) + half*1024 + pbase + m*16 + kb*4;
          uint2 st;
          st.x = pkrtz(pc[0], pc[1]);
          st.y = pkrtz(pc[2], pc[3]);
          *(uint2*)&cov[covbase] = st;
          #pragma unroll
          for (int r = 0; r < 4; r++){
            int bi = (m*16 + kb*4 + r) & 63;
            if (!((mwm >> bi) & 1)){ ssum += pc[r]; ssq += pc[r]*pc[r]; }
          }
        }
      }
      if (mt < 8){
        const unsigned long long mw = (mt < 4) ? mw0 : mw1;
        #pragma unroll
        for (int r = 0; r < 4; r += 2){
          int bi0 = (mt*16 + kb*4 + r)     & 63;
          int bi1 = (mt*16 + kb*4 + r + 1) & 63;
          float v0a = fmaxf(acc[mt][0][r]   + cb0, 0.f);
          float v1a = fmaxf(acc[mt][1][r]   + cb1, 0.f);
          float v0b = fmaxf(acc[mt][0][r+1] + cb0, 0.f);
          float v1b = fmaxf(acc[mt][1][r+1] + cb1, 0.f);
          if ((mw >> bi0) & 1){ v0a = 0.f; v1a = 0.f; }
          if ((mw >> bi1) & 1){ v0b = 0.f; v1b = 0.f; }
          sv[(kb*4 + r    )*20 + mrow] = pkrtz(v0a, v1a);
          sv[(kb*4 + r + 1)*20 + mrow] = pkrtz(v0b, v1b);
        }
      }
    }
  }

  // stats: fold kb groups (lanes mrow, mrow+16, mrow+32, mrow+48)
  ssum += __shfl_xor(ssum, 16);
  ssum += __shfl_xor(ssum, 32);
  ssq  += __shfl_xor(ssq, 16);
  ssq  += __shfl_xor(ssq, 32);
  if (lane < 8){
    atomicAdd(&slots[(bid & 7)*16 + lane],     ssum);
    atomicAdd(&slots[(bid & 7)*16 + 8 + lane], ssq);
  }
}

// ---------------- K_stats: finalize BN -> per-channel affine ---------------
__global__ void k_stats(const float* __restrict__ slots,
                        const float* __restrict__ cntp,
                        const float* __restrict__ gamma,
                        const float* __restrict__ beta,
                        float* __restrict__ ab)
{
  int tid = threadIdx.x;
  if (tid < 8){
    double s = 0.0, q = 0.0;
    for (int i = 0; i < 8; i++){
      s += (double)slots[i*16 + tid];
      q += (double)slots[i*16 + 8 + tid];
    }
    double cnt  = (double)fmaxf(*cntp, 1.0f);
    double mean = s / cnt;
    double var  = q / cnt - mean*mean;
    float inv = (float)(1.0 / sqrt(var + 1e-5));
    float A = gamma[tid] * inv;
    float Bc = beta[tid] - (float)mean * A;
    ab[tid]     = A;
    ab[8 + tid] = Bc;
  }
}

// ---------------- K_out: normalize + (b,t,n)->(b,n,t) permute --------------
__global__ void k_out(const unsigned short* __restrict__ cov,
                      const unsigned char* __restrict__ mB,
                      const float* __restrict__ ab,
                      float* __restrict__ out)
{
  size_t gid = (size_t)blockIdx.x * 256 + threadIdx.x;
  size_t e = gid * 8;                               // out element base
  int px = (int)(e & 2047);
  size_t r = e >> 11;
  int t = (int)(r & 127); r >>= 7;
  int n = (int)(r & 7);
  int b = (int)(r >> 3);
  const unsigned short* cp = cov + ((((size_t)b*T_ + t)*NH + n) << 11) + px;
  u16x8 cv = *(const u16x8*)cp;
  unsigned long long mm = *(const unsigned long long*)(mB + (size_t)b*L_ + px);
  float A = ab[n], Bc = ab[8 + n];
  float res[8];
  #pragma unroll
  for (int j = 0; j < 8; j++){
    float v = h2f(cv[j]);
    res[j] = ((mm >> (8*j)) & 0xFFull) ? v : (A*v + Bc);  // masked: raw (==0)
  }
  f32x4* o = (f32x4*)(out + e);
  o[0] = (f32x4){res[0], res[1], res[2], res[3]};
  o[1] = (f32x4){res[4], res[5], res[6], res[7]};
}

// ---------------------------------------------------------------------------
extern "C" void kernel_launch(void* const* d_in, const int* in_sizes, int n_in,
                              void* d_out, int out_size, void* d_ws, size_t ws_size,
                              hipStream_t stream)
{
  const float* prev  = (const float*)d_in[0];
  const float* curr  = (const float*)d_in[1];
  const void*  mraw  = d_in[2];
  // d_in[3] = h (unused, constant 32)
  const float* convw = (const float*)d_in[4];
  const float* convb = (const float*)d_in[5];
  const float* projw = (const float*)d_in[6];
  const float* gamma = (const float*)d_in[7];
  const float* beta  = (const float*)d_in[8];
  float* out = (float*)d_out;

  char* ws = (char*)d_ws;
  // layout (bytes): cumIn 67108864 | cov 33554432 | mB 16384 | Wt 26880 |
  //                 Pt 1024 | slots 512 | cnt 64 | ab 64
  unsigned short* cumIn = (unsigned short*)(ws);
  unsigned short* cov   = (unsigned short*)(ws + 67108864);
  unsigned char*  mB    = (unsigned char*) (ws + 100663296);
  unsigned short* Wt    = (unsigned short*)(ws + 100679680);
  unsigned short* Pt    = (unsigned short*)(ws + 100706560);
  float* slots          = (float*)(ws + 100707584);
  float* cntp           = (float*)(ws + 100708096);
  float* ab             = (float*)(ws + 100708160);
  if (ws_size < (size_t)100708224) return;   // clean failure if ws too small

  hipMemsetAsync(slots, 0, 640, stream);     // slots + cntp
  k_front <<<305,  256, 0, stream>>>(prev, curr, (uint2*)cumIn,
                                     convw, projw, mraw, Wt, Pt, mB, cntp);
  k_conv  <<<2048, 256, 0, stream>>>(cumIn, Wt, Pt, mB, convb, cov, slots);
  k_stats <<<1,    64,  0, stream>>>(slots, cntp, gamma, beta, ab);
  k_out   <<<8192, 256, 0, stream>>>(cov, mB, ab, out);
}

// Round 11
// 183.926 us; speedup vs baseline: 1.0749x; 1.0309x over previous
//
#include <hip/hip_runtime.h>
#include <hip/hip_bf16.h>

// AttentionRefinementModule: cumsum(excl,t) -> conv5x5(16->32) -> +b,relu ->
// mask0 -> 1x1 proj(32->8) -> masked BN -> permute.
// cumsum inputs first (conv commutes with cumsum); MFMA conv over 1024 images.
// R11: R6 champion restored (114.3us k_conv). Adds: (1) wave-phase desync —
// odd waves run the 13-step ks sequence rotated by 6 (constant-unrolled, no
// runtime indexing) to break the lock-step that serializes the CU-shared LDS
// pipe vs MFMA pipe (utils summed to ~100%); (2) v_perm staging pack + pkrtz
// epilogue (VALU trims, proven safe); (3) cumsum at 2px/thread, 8 waves/CU.
// Closed arcs: ILP-pipeline (spills), occupancy 2/3/4 w/SIMD (flat ~114),
// swizzle/layout (conflict counter immovable at 5.14e6).

typedef __attribute__((ext_vector_type(4))) float f32x4;
typedef __attribute__((ext_vector_type(2))) float f32x2;
typedef __attribute__((ext_vector_type(8))) short short8;
typedef __attribute__((ext_vector_type(8))) unsigned short u16x8;

#define B_   8
#define NH   8
#define T_   128
#define H_   32
#define W_   64
#define L_   2048
#define CIN  16
#define DCC  32
#define WSTR 420   // K stride (elems) of weight rows (416 used + pad)

__device__ __forceinline__ unsigned short f2h(float f){
  _Float16 h = (_Float16)f;
  return __builtin_bit_cast(unsigned short, h);
}
__device__ __forceinline__ float h2f(unsigned short u){
  _Float16 h = __builtin_bit_cast(_Float16, u);
  return (float)h;
}
__device__ __forceinline__ unsigned pkrtz(float a, float b){
  return __builtin_bit_cast(unsigned, __builtin_amdgcn_cvt_pkrtz(a, b));
}
// 2-bit swizzle: bits[4:5] ^= bits[7:8]. Adding multiples of 512 commutes,
// so ds_read immediate offsets (mt steps of 512 B) remain valid.
__device__ __forceinline__ int swz(int a){ return a ^ ((a >> 3) & 0x30); }

// ---------------- K_front: cumsum (blocks 0..511) + prep (512..560) --------
__global__ void k_front(const float* __restrict__ prev,
                        const float* __restrict__ curr,
                        unsigned* __restrict__ cum1,
                        const float* __restrict__ convw,
                        const float* __restrict__ projw,
                        const void* __restrict__ mraw,
                        unsigned short* __restrict__ Wt,
                        unsigned short* __restrict__ Pt,
                        unsigned char* __restrict__ mB,
                        float* __restrict__ cntOut)
{
  int tid = threadIdx.x;
  int blk = blockIdx.x;
  if (blk < 512){
    // exclusive cumsum over t, fp32 -> fp16, 2 px/thread (8 waves/CU)
    int gid = blk * 256 + tid;                   // 0..131071
    int p2 = gid & 1023;                         // pair: px = 2*p2
    int ci = (gid >> 10) & 15;
    int b  = gid >> 14;
    const float* src = ((ci < 8)
        ? prev + ((size_t)(b*8 + ci) * T_) * L_
        : curr + ((size_t)(b*8 + ci - 8) * T_) * L_) + p2*2;
    unsigned* dst = cum1 + ((size_t)(b*CIN + ci) * T_) * (L_/2) + p2;
    float a0 = 0.f, a1 = 0.f;
    #pragma unroll 8
    for (int t = 0; t < T_; t++){
      dst[(size_t)t * (L_/2)] = (unsigned)f2h(a0) | ((unsigned)f2h(a1) << 16);
      f32x2 v = *(const f32x2*)(src + (size_t)t * L_);
      a0 += v.x; a1 += v.y;
    }
    return;
  }
  int blk2 = blk - 512;
  if (blk2 < 32){
    // Wt row co, dy-paired K layout:
    // k = g*32 + kb*8 + j ; h = kb>>1 ; ci = (kb&1)*8 + j
    // g<10: dx = g>>1, dy = (g&1)*2 + h
    // g>=10: dy = 4, dx = 2*(g-10) + h  (dx>4 => zero pad)
    int co = blk2;
    for (int k = tid; k < WSTR; k += 256){
      float v = 0.f;
      if (k < 416){
        int g  = k >> 5, kk = k & 31;
        int kb = kk >> 3, j = kk & 7;
        int ci = (kb & 1)*8 + j;
        int h  = kb >> 1;
        int dy, dx, valid = 1;
        if (g < 10){ dx = g >> 1; dy = (g & 1)*2 + h; }
        else { dy = 4; dx = 2*(g - 10) + h; if (dx > 4) valid = 0; }
        if (valid) v = convw[(((co*CIN + ci)*5 + dy)*5) + dx];
      }
      Wt[co*WSTR + k] = f2h(v);
    }
  } else if (blk2 == 32){
    // Pt[n][q] 16x32, rows 8..15 zero, col-permuted: q -> co = 16*(q&1)+(q>>1)
    for (int idx = tid; idx < 16*32; idx += 256){
      int n = idx >> 5, q = idx & 31;
      float v = (n < 8) ? projw[n*32 + 16*(q & 1) + (q >> 1)] : 0.f;
      Pt[idx] = f2h(v);
    }
  } else {
    __shared__ int s_flags;
    __shared__ int s_cnt;
    if (tid == 0){ s_flags = 0; s_cnt = 0; }
    __syncthreads();
    const unsigned* w = (const unsigned*)mraw;
    int fl = 0;
    for (int i = tid; i < 4096; i += 256){       // scan 16KB worth of words
      unsigned v = w[i];
      if (v == 0x3F800000u) fl |= 2;             // float 1.0 pattern
      else if (v > 1u)      fl |= 1;             // packed-byte pattern
      else if (v == 1u)     fl |= 4;             // i32 "true" pattern
    }
    if (fl) atomicOr(&s_flags, fl);
    __syncthreads();
    int flags = s_flags;
    int mode = (flags & 1) ? 0 : ((flags & 2) ? 2 : ((flags & 4) ? 1 : 0));
    int c = 0;
    int base = (blk2 - 33) * 1024;
    for (int k = 0; k < 4; k++){
      int i = base + k*256 + tid;
      int m;
      if (mode == 0)      m = (((const unsigned char*)mraw)[i] != 0);
      else if (mode == 2) m = (((const float*)mraw)[i] != 0.f);
      else                m = (((const int*)mraw)[i] != 0);
      mB[i] = (unsigned char)m;
      c += 1 - m;
    }
    atomicAdd(&s_cnt, c);
    __syncthreads();
    if (tid == 0) atomicAdd(cntOut, 128.0f * (float)s_cnt);
  }
}

// ---------------- K_conv: MFMA conv + bias/relu/mask + proj + stats --------
// One block = half of one (b,t) image (16 rows). 4 waves x 256px each.
// Weights read from global (L1-resident, 26.9KB); img staged in LDS.
__global__ __launch_bounds__(256, 3) void k_conv(
    const unsigned short* __restrict__ cumIn,
    const unsigned short* __restrict__ Wt,
    const unsigned short* __restrict__ Pt,
    const unsigned char* __restrict__ mB,
    const float* __restrict__ convb,
    unsigned short* __restrict__ cov,
    float* __restrict__ slots)
{
  __shared__ alignas(16) unsigned short img[20*68*16];   // swizzled, 43520 B
  __shared__ alignas(16) unsigned short plds[16*32];     // 1024 B
  __shared__ alignas(16) unsigned sval[4][16*20];        // per-wave packed, 5120 B
  __shared__ unsigned long long mbl[16];                 // bit mask, 1024 px

  const int tid  = threadIdx.x;
  const int bid  = blockIdx.x;
  const int half = bid & 1;
  const int bt   = bid >> 1;
  const int t    = bt & 127;
  const int b    = bt >> 7;
  const int ylo  = half * 16;
  const int lane = tid & 63;
  const int wv   = tid >> 6;
  const int mrow = lane & 15;
  const int kb   = lane >> 4;

  // mask bits for this half-image: wave 0 ballots 16 x 64 px
  if (wv == 0){
    #pragma unroll
    for (int k2 = 0; k2 < 16; k2++){
      int m = mB[b*L_ + half*1024 + k2*64 + lane];
      unsigned long long bal = __ballot(m != 0);
      if (lane == 0) mbl[k2] = bal;
    }
  } else if (wv == 1){
    const uint4* srcp = (const uint4*)Pt;
    uint4* dstp = (uint4*)plds;
    for (int i = lane; i < 64; i += 64) dstp[i] = srcp[i];
  }

  // zero-fill x-halo columns (x in {-2,-1,64,65} is always OOB -> 0)
  for (int it = tid; it < 640; it += 256){
    int cp  = it & 7;
    int xxi = (it >> 3) & 3;
    int yy  = it >> 5;                       // 0..19
    int xx  = (xxi < 2) ? xxi : 64 + xxi;    // 0,1,66,67
    int ad  = ((yy*68 + xx)*16 + 2*cp)*2;
    *(unsigned*)((char*)img + swz(ad)) = 0u;
  }
  // stage interior: thread = (yy, ci-pair, x-chunk of 8); 16B coalesced loads,
  // b32 LDS writes (2 ci packed via v_perm), 2-bit swizzle
  #pragma unroll
  for (int iter = 0; iter < 5; iter++){
    int it = iter*256 + tid;                 // 0..1279
    int xc = it & 7;
    int cp = (it >> 3) & 7;
    int yy = it >> 6;                        // 0..19
    int y  = ylo - 2 + yy;
    uint4 r0 = (uint4){0,0,0,0}, r1 = (uint4){0,0,0,0};
    if (y >= 0 && y < H_){
      const unsigned short* rp = cumIn + (((size_t)(b*CIN + 2*cp) * T_ + t) * L_) + y*W_ + xc*8;
      r0 = *(const uint4*)rp;
      r1 = *(const uint4*)(rp + (size_t)T_ * L_);   // next ci plane
    }
    int sbase = ((yy*68 + 2 + xc*8)*16 + 2*cp)*2;
    unsigned rr0[4] = {r0.x, r0.y, r0.z, r0.w};
    unsigned rr1[4] = {r1.x, r1.y, r1.z, r1.w};
    #pragma unroll
    for (int d = 0; d < 4; d++){
      unsigned wl = __builtin_amdgcn_perm(rr1[d], rr0[d], 0x05040100u); // j=2d
      unsigned wh = __builtin_amdgcn_perm(rr1[d], rr0[d], 0x07060302u); // j=2d+1
      *(unsigned*)((char*)img + swz(sbase + (2*d  )*32)) = wl;
      *(unsigned*)((char*)img + swz(sbase + (2*d+1)*32)) = wh;
    }
  }
  __syncthreads();

  const float cb0 = convb[mrow];
  const float cb1 = convb[mrow + 16];
  const short8 pbf = *(const short8*)&plds[mrow*32 + kb*8];  // proj B-frag
  const unsigned short* Wg = Wt + mrow*WSTR + kb*8;          // weight row base
  const char* imgc = (const char*)img;

  // per-lane tap byte-offsets for all 13 k-groups (dy-paired layout)
  int offs_[13];
  {
    const int h = kb >> 1;
    #pragma unroll
    for (int g = 0; g < 13; g++){
      int dy, dx;
      if (g < 10){ dx = g >> 1; dy = (g & 1)*2 + h; }
      else { dy = 4; dx = 2*(g - 10) + h; if (dx > 4) dx = 4; } // pad: W=0
      offs_[g] = (dy*68 + dx)*32 + (kb & 1)*16;
    }
  }

  float ssum = 0.f, ssq = 0.f;

  #pragma unroll 1
  for (int c = 0; c < 2; c++){
    // opaque zero: keeps B-loads inside the c-loop (blocks LICM => VGPR fit)
    int wofs = 0;
    asm volatile("" : "+v"(wofs));
    const int pbase = wv*256 + c*128;
    const unsigned long long mw0 = mbl[(pbase >> 6)];
    const unsigned long long mw1 = mbl[(pbase >> 6) + 1];
    const int base_u = ((pbase >> 6)*68 + mrow)*32;   // unswizzled byte base
    f32x4 acc[8][2];
    #pragma unroll
    for (int mt = 0; mt < 8; mt++){ acc[mt][0] = (f32x4)0.f; acc[mt][1] = (f32x4)0.f; }

    // one ks step, constant ks (compile-time offsets/indices)
    #define KSTEP(ks) do { \
      short8 bfa = *(const short8*)(Wg + wofs + (ks)*32); \
      short8 bfb = *(const short8*)(Wg + wofs + 6720 + (ks)*32); \
      const char* p0 = imgc + swz(base_u + offs_[(ks)]); \
      const char* p1 = imgc + swz(base_u + 2176 + offs_[(ks)]); \
      short8 a[8]; \
      a[0] = *(const short8*)(p0); \
      a[1] = *(const short8*)(p0 + 512); \
      a[2] = *(const short8*)(p0 + 1024); \
      a[3] = *(const short8*)(p0 + 1536); \
      a[4] = *(const short8*)(p1); \
      a[5] = *(const short8*)(p1 + 512); \
      a[6] = *(const short8*)(p1 + 1024); \
      a[7] = *(const short8*)(p1 + 1536); \
      __builtin_amdgcn_s_setprio(1); \
      _Pragma("unroll") \
      for (int mt = 0; mt < 8; mt++){ \
        acc[mt][0] = __builtin_amdgcn_mfma_f32_16x16x32_f16(a[mt], bfa, acc[mt][0], 0, 0, 0); \
        acc[mt][1] = __builtin_amdgcn_mfma_f32_16x16x32_f16(a[mt], bfb, acc[mt][1], 0, 0, 0); \
      } \
      __builtin_amdgcn_s_setprio(0); \
    } while (0)

    // wave-phase desync: odd waves run the ks sequence rotated by 6 so their
    // LDS-read phase overlaps even waves' MFMA phase (fp32 sum reorder only).
    if ((wv & 1) == 0){
      KSTEP(0); KSTEP(1); KSTEP(2); KSTEP(3); KSTEP(4); KSTEP(5); KSTEP(6);
      KSTEP(7); KSTEP(8); KSTEP(9); KSTEP(10); KSTEP(11); KSTEP(12);
    } else {
      KSTEP(6); KSTEP(7); KSTEP(8); KSTEP(9); KSTEP(10); KSTEP(11); KSTEP(12);
      KSTEP(0); KSTEP(1); KSTEP(2); KSTEP(3); KSTEP(4); KSTEP(5);
    }
    #undef KSTEP

    // epilogue: bias+relu+mask -> packed fp16 pairs in sval (transpose) ->
    // proj MFMA (K=32, P columns pre-permuted) -> cov store + stats.
    // Single buffer: proj(mt-1) reads are issued BEFORE store(mt) writes;
    // same-wave LDS ops complete in order, compiler preserves aliased order.
    unsigned* sv = &sval[wv][0];
    #pragma unroll
    for (int mt = 0; mt <= 8; mt++){
      if (mt >= 1){
        const int m = mt - 1;
        short8 pa = *(const short8*)&sv[mrow*20 + kb*4];
        f32x4 pc = (f32x4)0.f;
        pc = __builtin_amdgcn_mfma_f32_16x16x32_f16(pa, pbf, pc, 0, 0, 0);
        if (mrow < 8){
          const unsigned long long mwm = (m < 4) ? mw0 : mw1;
          size_t covbase = (((size_t)bt*NH + mrow) * L_) + half*1024 + pbase + m*16 + kb*4;
          uint2 st;
          st.x = pkrtz(pc[0], pc[1]);
          st.y = pkrtz(pc[2], pc[3]);
          *(uint2*)&cov[covbase] = st;
          #pragma unroll
          for (int r = 0; r < 4; r++){
            int bi = (m*16 + kb*4 + r) & 63;
            if (!((mwm >> bi) & 1)){ ssum += pc[r]; ssq += pc[r]*pc[r]; }
          }
        }
      }
      if (mt < 8){
        const unsigned long long mw = (mt < 4) ? mw0 : mw1;
        #pragma unroll
        for (int r = 0; r < 4; r += 2){
          int bi0 = (mt*16 + kb*4 + r)     & 63;
          int bi1 = (mt*16 + kb*4 + r + 1) & 63;
          float v0a = fmaxf(acc[mt][0][r]   + cb0, 0.f);
          float v1a = fmaxf(acc[mt][1][r]   + cb1, 0.f);
          float v0b = fmaxf(acc[mt][0][r+1] + cb0, 0.f);
          float v1b = fmaxf(acc[mt][1][r+1] + cb1, 0.f);
          if ((mw >> bi0) & 1){ v0a = 0.f; v1a = 0.f; }
          if ((mw >> bi1) & 1){ v0b = 0.f; v1b = 0.f; }
          sv[(kb*4 + r    )*20 + mrow] = pkrtz(v0a, v1a);
          sv[(kb*4 + r + 1)*20 + mrow] = pkrtz(v0b, v1b);
        }
      }
    }
  }

  // stats: fold kb groups (lanes mrow, mrow+16, mrow+32, mrow+48)
  ssum += __shfl_xor(ssum, 16);
  ssum += __shfl_xor(ssum, 32);
  ssq  += __shfl_xor(ssq, 16);
  ssq  += __shfl_xor(ssq, 32);
  if (lane < 8){
    atomicAdd(&slots[(bid & 7)*16 + lane],     ssum);
    atomicAdd(&slots[(bid & 7)*16 + 8 + lane], ssq);
  }
}

// ---------------- K_stats: finalize BN -> per-channel affine ---------------
__global__ void k_stats(const float* __restrict__ slots,
                        const float* __restrict__ cntp,
                        const float* __restrict__ gamma,
                        const float* __restrict__ beta,
                        float* __restrict__ ab)
{
  int tid = threadIdx.x;
  if (tid < 8){
    double s = 0.0, q = 0.0;
    for (int i = 0; i < 8; i++){
      s += (double)slots[i*16 + tid];
      q += (double)slots[i*16 + 8 + tid];
    }
    double cnt  = (double)fmaxf(*cntp, 1.0f);
    double mean = s / cnt;
    double var  = q / cnt - mean*mean;
    float inv = (float)(1.0 / sqrt(var + 1e-5));
    float A = gamma[tid] * inv;
    float Bc = beta[tid] - (float)mean * A;
    ab[tid]     = A;
    ab[8 + tid] = Bc;
  }
}

// ---------------- K_out: normalize + (b,t,n)->(b,n,t) permute --------------
__global__ void k_out(const unsigned short* __restrict__ cov,
                      const unsigned char* __restrict__ mB,
                      const float* __restrict__ ab,
                      float* __restrict__ out)
{
  size_t gid = (size_t)blockIdx.x * 256 + threadIdx.x;
  size_t e = gid * 8;                               // out element base
  int px = (int)(e & 2047);
  size_t r = e >> 11;
  int t = (int)(r & 127); r >>= 7;
  int n = (int)(r & 7);
  int b = (int)(r >> 3);
  const unsigned short* cp = cov + ((((size_t)b*T_ + t)*NH + n) << 11) + px;
  u16x8 cv = *(const u16x8*)cp;
  unsigned long long mm = *(const unsigned long long*)(mB + (size_t)b*L_ + px);
  float A = ab[n], Bc = ab[8 + n];
  float res[8];
  #pragma unroll
  for (int j = 0; j < 8; j++){
    float v = h2f(cv[j]);
    res[j] = ((mm >> (8*j)) & 0xFFull) ? v : (A*v + Bc);  // masked: raw (==0)
  }
  f32x4* o = (f32x4*)(out + e);
  o[0] = (f32x4){res[0], res[1], res[2], res[3]};
  o[1] = (f32x4){res[4], res[5], res[6], res[7]};
}

// ---------------------------------------------------------------------------
extern "C" void kernel_launch(void* const* d_in, const int* in_sizes, int n_in,
                              void* d_out, int out_size, void* d_ws, size_t ws_size,
                              hipStream_t stream)
{
  const float* prev  = (const float*)d_in[0];
  const float* curr  = (const float*)d_in[1];
  const void*  mraw  = d_in[2];
  // d_in[3] = h (unused, constant 32)
  const float* convw = (const float*)d_in[4];
  const float* convb = (const float*)d_in[5];
  const float* projw = (const float*)d_in[6];
  const float* gamma = (const float*)d_in[7];
  const float* beta  = (const float*)d_in[8];
  float* out = (float*)d_out;

  char* ws = (char*)d_ws;
  // layout (bytes): cumIn 67108864 | cov 33554432 | mB 16384 | Wt 26880 |
  //                 Pt 1024 | slots 512 | cnt 64 | ab 64
  unsigned short* cumIn = (unsigned short*)(ws);
  unsigned short* cov   = (unsigned short*)(ws + 67108864);
  unsigned char*  mB    = (unsigned char*) (ws + 100663296);
  unsigned short* Wt    = (unsigned short*)(ws + 100679680);
  unsigned short* Pt    = (unsigned short*)(ws + 100706560);
  float* slots          = (float*)(ws + 100707584);
  float* cntp           = (float*)(ws + 100708096);
  float* ab             = (float*)(ws + 100708160);
  if (ws_size < (size_t)100708224) return;   // clean failure if ws too small

  hipMemsetAsync(slots, 0, 640, stream);     // slots + cntp
  k_front <<<561,  256, 0, stream>>>(prev, curr, (unsigned*)cumIn,
                                     convw, projw, mraw, Wt, Pt, mB, cntp);
  k_conv  <<<2048, 256, 0, stream>>>(cumIn, Wt, Pt, mB, convb, cov, slots);
  k_stats <<<1,    64,  0, stream>>>(slots, cntp, gamma, beta, ab);
  k_out   <<<8192, 256, 0, stream>>>(cov, mB, ab, out);
}

// Round 12
// 167.707 us; speedup vs baseline: 1.1788x; 1.0967x over previous
//
#include <hip/hip_runtime.h>
#include <hip/hip_bf16.h>

// AttentionRefinementModule: cumsum(excl,t) -> conv5x5(16->32) -> +b,relu ->
// mask0 -> 1x1 proj(32->8) -> masked BN -> permute.
// cumsum inputs first (conv commutes with cumsum); MFMA conv over 1024 images.
// R12: k_conv restored BYTE-IDENTICAL to R6 (measured 114.2us champion).
// Every deviation measured worse: 3-bit swz (+6), alias fold (+6), B-prefetch
// (+6), no-setprio (+6), 8-row blocks (+31), reg-spend (spill, +21), desync
// (I$ blowup, +16), v_perm/pkrtz trims (~+6, mis-attributed in R7/R8).
// Only retained change: k_front cumsum at 2px/thread (isolated kernel, ~-3us).

typedef __attribute__((ext_vector_type(4))) float f32x4;
typedef __attribute__((ext_vector_type(2))) float f32x2;
typedef __attribute__((ext_vector_type(8))) short short8;
typedef __attribute__((ext_vector_type(8))) unsigned short u16x8;

#define B_   8
#define NH   8
#define T_   128
#define H_   32
#define W_   64
#define L_   2048
#define CIN  16
#define DCC  32
#define WSTR 420   // K stride (elems) of weight rows (416 used + pad)

__device__ __forceinline__ unsigned short f2h(float f){
  _Float16 h = (_Float16)f;
  return __builtin_bit_cast(unsigned short, h);
}
__device__ __forceinline__ float h2f(unsigned short u){
  _Float16 h = __builtin_bit_cast(_Float16, u);
  return (float)h;
}
// 2-bit swizzle: bits[4:5] ^= bits[7:8]. Adding multiples of 512 commutes,
// so ds_read immediate offsets (mt steps of 512 B) remain valid.
__device__ __forceinline__ int swz(int a){ return a ^ ((a >> 3) & 0x30); }

// ---------------- K_front: cumsum (blocks 0..511) + prep (512..560) --------
__global__ void k_front(const float* __restrict__ prev,
                        const float* __restrict__ curr,
                        unsigned* __restrict__ cum1,
                        const float* __restrict__ convw,
                        const float* __restrict__ projw,
                        const void* __restrict__ mraw,
                        unsigned short* __restrict__ Wt,
                        unsigned short* __restrict__ Pt,
                        unsigned char* __restrict__ mB,
                        float* __restrict__ cntOut)
{
  int tid = threadIdx.x;
  int blk = blockIdx.x;
  if (blk < 512){
    // exclusive cumsum over t, fp32 -> fp16, 2 px/thread (8 waves/CU)
    int gid = blk * 256 + tid;                   // 0..131071
    int p2 = gid & 1023;                         // pair: px = 2*p2
    int ci = (gid >> 10) & 15;
    int b  = gid >> 14;
    const float* src = ((ci < 8)
        ? prev + ((size_t)(b*8 + ci) * T_) * L_
        : curr + ((size_t)(b*8 + ci - 8) * T_) * L_) + p2*2;
    unsigned* dst = cum1 + ((size_t)(b*CIN + ci) * T_) * (L_/2) + p2;
    float a0 = 0.f, a1 = 0.f;
    #pragma unroll 8
    for (int t = 0; t < T_; t++){
      dst[(size_t)t * (L_/2)] = (unsigned)f2h(a0) | ((unsigned)f2h(a1) << 16);
      f32x2 v = *(const f32x2*)(src + (size_t)t * L_);
      a0 += v.x; a1 += v.y;
    }
    return;
  }
  int blk2 = blk - 512;
  if (blk2 < 32){
    // Wt row co, dy-paired K layout:
    // k = g*32 + kb*8 + j ; h = kb>>1 ; ci = (kb&1)*8 + j
    // g<10: dx = g>>1, dy = (g&1)*2 + h
    // g>=10: dy = 4, dx = 2*(g-10) + h  (dx>4 => zero pad)
    int co = blk2;
    for (int k = tid; k < WSTR; k += 256){
      float v = 0.f;
      if (k < 416){
        int g  = k >> 5, kk = k & 31;
        int kb = kk >> 3, j = kk & 7;
        int ci = (kb & 1)*8 + j;
        int h  = kb >> 1;
        int dy, dx, valid = 1;
        if (g < 10){ dx = g >> 1; dy = (g & 1)*2 + h; }
        else { dy = 4; dx = 2*(g - 10) + h; if (dx > 4) valid = 0; }
        if (valid) v = convw[(((co*CIN + ci)*5 + dy)*5) + dx];
      }
      Wt[co*WSTR + k] = f2h(v);
    }
  } else if (blk2 == 32){
    // Pt[n][q] 16x32, rows 8..15 zero, col-permuted: q -> co = 16*(q&1)+(q>>1)
    for (int idx = tid; idx < 16*32; idx += 256){
      int n = idx >> 5, q = idx & 31;
      float v = (n < 8) ? projw[n*32 + 16*(q & 1) + (q >> 1)] : 0.f;
      Pt[idx] = f2h(v);
    }
  } else {
    __shared__ int s_flags;
    __shared__ int s_cnt;
    if (tid == 0){ s_flags = 0; s_cnt = 0; }
    __syncthreads();
    const unsigned* w = (const unsigned*)mraw;
    int fl = 0;
    for (int i = tid; i < 4096; i += 256){       // scan 16KB worth of words
      unsigned v = w[i];
      if (v == 0x3F800000u) fl |= 2;             // float 1.0 pattern
      else if (v > 1u)      fl |= 1;             // packed-byte pattern
      else if (v == 1u)     fl |= 4;             // i32 "true" pattern
    }
    if (fl) atomicOr(&s_flags, fl);
    __syncthreads();
    int flags = s_flags;
    int mode = (flags & 1) ? 0 : ((flags & 2) ? 2 : ((flags & 4) ? 1 : 0));
    int c = 0;
    int base = (blk2 - 33) * 1024;
    for (int k = 0; k < 4; k++){
      int i = base + k*256 + tid;
      int m;
      if (mode == 0)      m = (((const unsigned char*)mraw)[i] != 0);
      else if (mode == 2) m = (((const float*)mraw)[i] != 0.f);
      else                m = (((const int*)mraw)[i] != 0);
      mB[i] = (unsigned char)m;
      c += 1 - m;
    }
    atomicAdd(&s_cnt, c);
    __syncthreads();
    if (tid == 0) atomicAdd(cntOut, 128.0f * (float)s_cnt);
  }
}

// ---------------- K_conv: MFMA conv + bias/relu/mask + proj + stats --------
// One block = half of one (b,t) image (16 rows). 4 waves x 256px each.
// Weights read from global (L1-resident, 26.9KB); img staged in LDS.
__global__ __launch_bounds__(256, 3) void k_conv(
    const unsigned short* __restrict__ cumIn,
    const unsigned short* __restrict__ Wt,
    const unsigned short* __restrict__ Pt,
    const unsigned char* __restrict__ mB,
    const float* __restrict__ convb,
    unsigned short* __restrict__ cov,
    float* __restrict__ slots)
{
  __shared__ alignas(16) unsigned short img[20*68*16];   // swizzled, 43520 B
  __shared__ alignas(16) unsigned short plds[16*32];     // 1024 B
  __shared__ alignas(16) unsigned sval[4][16*20];        // per-wave packed, 5120 B
  __shared__ unsigned long long mbl[16];                 // bit mask, 1024 px

  const int tid  = threadIdx.x;
  const int bid  = blockIdx.x;
  const int half = bid & 1;
  const int bt   = bid >> 1;
  const int t    = bt & 127;
  const int b    = bt >> 7;
  const int ylo  = half * 16;
  const int lane = tid & 63;
  const int wv   = tid >> 6;
  const int mrow = lane & 15;
  const int kb   = lane >> 4;

  // mask bits for this half-image: wave 0 ballots 16 x 64 px
  if (wv == 0){
    #pragma unroll
    for (int k2 = 0; k2 < 16; k2++){
      int m = mB[b*L_ + half*1024 + k2*64 + lane];
      unsigned long long bal = __ballot(m != 0);
      if (lane == 0) mbl[k2] = bal;
    }
  } else if (wv == 1){
    const uint4* srcp = (const uint4*)Pt;
    uint4* dstp = (uint4*)plds;
    for (int i = lane; i < 64; i += 64) dstp[i] = srcp[i];
  }

  // zero-fill x-halo columns (x in {-2,-1,64,65} is always OOB -> 0)
  for (int it = tid; it < 640; it += 256){
    int cp  = it & 7;
    int xxi = (it >> 3) & 3;
    int yy  = it >> 5;                       // 0..19
    int xx  = (xxi < 2) ? xxi : 64 + xxi;    // 0,1,66,67
    int ad  = ((yy*68 + xx)*16 + 2*cp)*2;
    *(unsigned*)((char*)img + swz(ad)) = 0u;
  }
  // stage interior: thread = (yy, ci-pair, x-chunk of 8); 16B coalesced loads,
  // b32 LDS writes (2 ci packed), 2-bit swizzle
  #pragma unroll
  for (int iter = 0; iter < 5; iter++){
    int it = iter*256 + tid;                 // 0..1279
    int xc = it & 7;
    int cp = (it >> 3) & 7;
    int yy = it >> 6;                        // 0..19
    int y  = ylo - 2 + yy;
    u16x8 v0 = (u16x8)0, v1 = (u16x8)0;
    if (y >= 0 && y < H_){
      const unsigned short* r0 = cumIn + (((size_t)(b*CIN + 2*cp) * T_ + t) * L_) + y*W_ + xc*8;
      v0 = *(const u16x8*)r0;
      v1 = *(const u16x8*)(r0 + (size_t)T_ * L_);   // next ci plane
    }
    int sbase = ((yy*68 + 2 + xc*8)*16 + 2*cp)*2;
    #pragma unroll
    for (int j = 0; j < 8; j++){
      unsigned wd = (unsigned)v0[j] | ((unsigned)v1[j] << 16);
      int ad = sbase + j*32;
      *(unsigned*)((char*)img + swz(ad)) = wd;
    }
  }
  __syncthreads();

  const float cb0 = convb[mrow];
  const float cb1 = convb[mrow + 16];
  const short8 pbf = *(const short8*)&plds[mrow*32 + kb*8];  // proj B-frag
  const unsigned short* Wg = Wt + mrow*WSTR + kb*8;          // weight row base
  const char* imgc = (const char*)img;

  // per-lane tap byte-offsets for all 13 k-groups (dy-paired layout)
  int offs_[13];
  {
    const int h = kb >> 1;
    #pragma unroll
    for (int g = 0; g < 13; g++){
      int dy, dx;
      if (g < 10){ dx = g >> 1; dy = (g & 1)*2 + h; }
      else { dy = 4; dx = 2*(g - 10) + h; if (dx > 4) dx = 4; } // pad: W=0
      offs_[g] = (dy*68 + dx)*32 + (kb & 1)*16;
    }
  }

  float ssum = 0.f, ssq = 0.f;

  #pragma unroll 1
  for (int c = 0; c < 2; c++){
    // opaque zero: keeps B-loads inside the c-loop (blocks LICM => VGPR fit)
    int wofs = 0;
    asm volatile("" : "+v"(wofs));
    const int pbase = wv*256 + c*128;
    const unsigned long long mw0 = mbl[(pbase >> 6)];
    const unsigned long long mw1 = mbl[(pbase >> 6) + 1];
    const int base_u = ((pbase >> 6)*68 + mrow)*32;   // unswizzled byte base
    f32x4 acc[8][2];
    #pragma unroll
    for (int mt = 0; mt < 8; mt++){ acc[mt][0] = (f32x4)0.f; acc[mt][1] = (f32x4)0.f; }

    #pragma unroll
    for (int ks = 0; ks < 13; ks++){
      short8 bfa = *(const short8*)(Wg + wofs + ks*32);          // co 0..15
      short8 bfb = *(const short8*)(Wg + wofs + 6720 + ks*32);   // co 16..31
      const char* p0 = imgc + swz(base_u + offs_[ks]);
      const char* p1 = imgc + swz(base_u + 2176 + offs_[ks]);
      short8 a[8];
      a[0] = *(const short8*)(p0);
      a[1] = *(const short8*)(p0 + 512);
      a[2] = *(const short8*)(p0 + 1024);
      a[3] = *(const short8*)(p0 + 1536);
      a[4] = *(const short8*)(p1);
      a[5] = *(const short8*)(p1 + 512);
      a[6] = *(const short8*)(p1 + 1024);
      a[7] = *(const short8*)(p1 + 1536);
      __builtin_amdgcn_s_setprio(1);
      #pragma unroll
      for (int mt = 0; mt < 8; mt++){
        acc[mt][0] = __builtin_amdgcn_mfma_f32_16x16x32_f16(a[mt], bfa, acc[mt][0], 0, 0, 0);
        acc[mt][1] = __builtin_amdgcn_mfma_f32_16x16x32_f16(a[mt], bfb, acc[mt][1], 0, 0, 0);
      }
      __builtin_amdgcn_s_setprio(0);
    }

    // epilogue: bias+relu+mask -> packed fp16 pairs in sval (transpose) ->
    // proj MFMA (K=32, P columns pre-permuted) -> cov store + stats.
    // Single buffer: proj(mt-1) reads are issued BEFORE store(mt) writes;
    // same-wave LDS ops complete in order, compiler preserves aliased order.
    unsigned* sv = &sval[wv][0];
    #pragma unroll
    for (int mt = 0; mt <= 8; mt++){
      if (mt >= 1){
        const int m = mt - 1;
        short8 pa = *(const short8*)&sv[mrow*20 + kb*4];
        f32x4 pc = (f32x4)0.f;
        pc = __builtin_amdgcn_mfma_f32_16x16x32_f16(pa, pbf, pc, 0, 0, 0);
        if (mrow < 8){
          const unsigned long long mwm = (m < 4) ? mw0 : mw1;
          size_t covbase = (((size_t)bt*NH + mrow) * L_) + half*1024 + pbase + m*16 + kb*4;
          uint2 st;
          st.x = (unsigned)f2h(pc[0]) | ((unsigned)f2h(pc[1]) << 16);
          st.y = (unsigned)f2h(pc[2]) | ((unsigned)f2h(pc[3]) << 16);
          *(uint2*)&cov[covbase] = st;
          #pragma unroll
          for (int r = 0; r < 4; r++){
            int bi = (m*16 + kb*4 + r) & 63;
            if (!((mwm >> bi) & 1)){ ssum += pc[r]; ssq += pc[r]*pc[r]; }
          }
        }
      }
      if (mt < 8){
        const unsigned long long mw = (mt < 4) ? mw0 : mw1;
        #pragma unroll
        for (int r = 0; r < 4; r++){
          int bi  = (mt*16 + kb*4 + r) & 63;
          int msk = (int)((mw >> bi) & 1);
          float v0 = fmaxf(acc[mt][0][r] + cb0, 0.f);
          float v1 = fmaxf(acc[mt][1][r] + cb1, 0.f);
          if (msk){ v0 = 0.f; v1 = 0.f; }
          unsigned pd = (unsigned)f2h(v0) | ((unsigned)f2h(v1) << 16);
          sv[(kb*4 + r)*20 + mrow] = pd;
        }
      }
    }
  }

  // stats: fold kb groups (lanes mrow, mrow+16, mrow+32, mrow+48)
  ssum += __shfl_xor(ssum, 16);
  ssum += __shfl_xor(ssum, 32);
  ssq  += __shfl_xor(ssq, 16);
  ssq  += __shfl_xor(ssq, 32);
  if (lane < 8){
    atomicAdd(&slots[(bid & 7)*16 + lane],     ssum);
    atomicAdd(&slots[(bid & 7)*16 + 8 + lane], ssq);
  }
}

// ---------------- K_stats: finalize BN -> per-channel affine ---------------
__global__ void k_stats(const float* __restrict__ slots,
                        const float* __restrict__ cntp,
                        const float* __restrict__ gamma,
                        const float* __restrict__ beta,
                        float* __restrict__ ab)
{
  int tid = threadIdx.x;
  if (tid < 8){
    double s = 0.0, q = 0.0;
    for (int i = 0; i < 8; i++){
      s += (double)slots[i*16 + tid];
      q += (double)slots[i*16 + 8 + tid];
    }
    double cnt  = (double)fmaxf(*cntp, 1.0f);
    double mean = s / cnt;
    double var  = q / cnt - mean*mean;
    float inv = (float)(1.0 / sqrt(var + 1e-5));
    float A = gamma[tid] * inv;
    float Bc = beta[tid] - (float)mean * A;
    ab[tid]     = A;
    ab[8 + tid] = Bc;
  }
}

// ---------------- K_out: normalize + (b,t,n)->(b,n,t) permute --------------
__global__ void k_out(const unsigned short* __restrict__ cov,
                      const unsigned char* __restrict__ mB,
                      const float* __restrict__ ab,
                      float* __restrict__ out)
{
  size_t gid = (size_t)blockIdx.x * 256 + threadIdx.x;
  size_t e = gid * 8;                               // out element base
  int px = (int)(e & 2047);
  size_t r = e >> 11;
  int t = (int)(r & 127); r >>= 7;
  int n = (int)(r & 7);
  int b = (int)(r >> 3);
  const unsigned short* cp = cov + ((((size_t)b*T_ + t)*NH + n) << 11) + px;
  u16x8 cv = *(const u16x8*)cp;
  unsigned long long mm = *(const unsigned long long*)(mB + (size_t)b*L_ + px);
  float A = ab[n], Bc = ab[8 + n];
  float res[8];
  #pragma unroll
  for (int j = 0; j < 8; j++){
    float v = h2f(cv[j]);
    res[j] = ((mm >> (8*j)) & 0xFFull) ? v : (A*v + Bc);  // masked: raw (==0)
  }
  f32x4* o = (f32x4*)(out + e);
  o[0] = (f32x4){res[0], res[1], res[2], res[3]};
  o[1] = (f32x4){res[4], res[5], res[6], res[7]};
}

// ---------------------------------------------------------------------------
extern "C" void kernel_launch(void* const* d_in, const int* in_sizes, int n_in,
                              void* d_out, int out_size, void* d_ws, size_t ws_size,
                              hipStream_t stream)
{
  const float* prev  = (const float*)d_in[0];
  const float* curr  = (const float*)d_in[1];
  const void*  mraw  = d_in[2];
  // d_in[3] = h (unused, constant 32)
  const float* convw = (const float*)d_in[4];
  const float* convb = (const float*)d_in[5];
  const float* projw = (const float*)d_in[6];
  const float* gamma = (const float*)d_in[7];
  const float* beta  = (const float*)d_in[8];
  float* out = (float*)d_out;

  char* ws = (char*)d_ws;
  // layout (bytes): cumIn 67108864 | cov 33554432 | mB 16384 | Wt 26880 |
  //                 Pt 1024 | slots 512 | cnt 64 | ab 64
  unsigned short* cumIn = (unsigned short*)(ws);
  unsigned short* cov   = (unsigned short*)(ws + 67108864);
  unsigned char*  mB    = (unsigned char*) (ws + 100663296);
  unsigned short* Wt    = (unsigned short*)(ws + 100679680);
  unsigned short* Pt    = (unsigned short*)(ws + 100706560);
  float* slots          = (float*)(ws + 100707584);
  float* cntp           = (float*)(ws + 100708096);
  float* ab             = (float*)(ws + 100708160);
  if (ws_size < (size_t)100708224) return;   // clean failure if ws too small

  hipMemsetAsync(slots, 0, 640, stream);     // slots + cntp
  k_front <<<561,  256, 0, stream>>>(prev, curr, (unsigned*)cumIn,
                                     convw, projw, mraw, Wt, Pt, mB, cntp);
  k_conv  <<<2048, 256, 0, stream>>>(cumIn, Wt, Pt, mB, convb, cov, slots);
  k_stats <<<1,    64,  0, stream>>>(slots, cntp, gamma, beta, ab);
  k_out   <<<8192, 256, 0, stream>>>(cov, mB, ab, out);
}